// Round 1
// baseline (485.149 us; speedup 1.0000x reference)
//
#include <hip/hip_runtime.h>
#include <hip/hip_bf16.h>

constexpr int N = 50000;
constexpr int E = 800000;
constexpr int D = 64;

struct BranchParams {
  const float* W[5];
  const float* b[5];
  const float* wa[5];
  const float* ba[5];
};

// Pass 1: axs[dst] += x[src]; deg[dst] += 1.  One wave per edge, lane = feature.
__global__ __launch_bounds__(256) void k_scatter1(
    const int* __restrict__ ei, const float* __restrict__ x,
    float* __restrict__ axs, float* __restrict__ deg) {
  int t = blockIdx.x * 256 + threadIdx.x;
  int e = t >> 6;
  int f = t & 63;
  if (e >= E) return;
  e = __builtin_amdgcn_readfirstlane(e);  // wave-uniform -> scalar loads
  int src = ei[e];
  int dst = ei[E + e];
  atomicAdd(&axs[dst * D + f], x[src * D + f]);
  if (f == 0) atomicAdd(&deg[dst], 1.0f);
}

// Pass 2: aaxs[dst] += axs[src] / max(deg[src],1).
__global__ __launch_bounds__(256) void k_scatter2(
    const int* __restrict__ ei, const float* __restrict__ axs,
    const float* __restrict__ deg, float* __restrict__ aaxs) {
  int t = blockIdx.x * 256 + threadIdx.x;
  int e = t >> 6;
  int f = t & 63;
  if (e >= E) return;
  e = __builtin_amdgcn_readfirstlane(e);
  int src = ei[e];
  int dst = ei[E + e];
  float inv = 1.0f / fmaxf(deg[src], 1.0f);
  atomicAdd(&aaxs[dst * D + f], axs[src * D + f] * inv);
}

// Fused per-node 5-branch GEMV + ReLU + sigmoid gate + gated sum.
// 16 nodes per block (4 waves x 4 nodes); one branch's W staged in LDS at a time.
__global__ __launch_bounds__(256) void k_branch(
    const float* __restrict__ x, const float* __restrict__ axs,
    const float* __restrict__ aaxs, const float* __restrict__ deg,
    BranchParams P, float* __restrict__ out) {
  __shared__ float Wlds[D * D];
  const int lane = threadIdx.x & 63;
  const int wid = threadIdx.x >> 6;
  const int nodeBase = blockIdx.x * 16 + wid * 4;  // N = 50000 = 3125 * 16, no tail

  float px[4], pax[4], paax[4], acc[4];
#pragma unroll
  for (int j = 0; j < 4; ++j) {
    int node = nodeBase + j;
    float inv = 1.0f / fmaxf(deg[node], 1.0f);
    px[j] = x[node * D + lane];
    pax[j] = axs[node * D + lane] * inv;    // mean-normalized A x
    paax[j] = aaxs[node * D + lane] * inv;  // mean-normalized A^2 x
    acc[j] = 0.0f;
  }

  for (int br = 0; br < 5; ++br) {
    __syncthreads();
#pragma unroll
    for (int i = threadIdx.x; i < D * D / 4; i += 256)
      ((float4*)Wlds)[i] = ((const float4*)P.W[br])[i];
    __syncthreads();
    const float bv = P.b[br][lane];
    const float wav = P.wa[br][lane];
    const float bav = P.ba[br][0];
#pragma unroll
    for (int j = 0; j < 4; ++j) {
      float p;
      switch (br) {
        case 0: p = px[j] - pax[j]; break;                      // hp
        case 1: p = pax[j]; break;                              // lp
        case 2: p = px[j]; break;                               // i
        case 3: p = px[j] - 2.0f * pax[j] + paax[j]; break;     // hp2
        default: p = paax[j]; break;                            // lp2
      }
      float h = bv;
#pragma unroll
      for (int k = 0; k < D; ++k) {
        float pk = __int_as_float(__builtin_amdgcn_readlane(__float_as_int(p), k));
        h = fmaf(pk, Wlds[k * D + lane], h);
      }
      h = fmaxf(h, 0.0f);
      float g = h * wav;
#pragma unroll
      for (int o = 32; o > 0; o >>= 1) g += __shfl_xor(g, o);
      float alpha = 1.0f / (1.0f + __expf(-(g + bav)));
      acc[j] = fmaf(alpha, h, acc[j]);
    }
  }
#pragma unroll
  for (int j = 0; j < 4; ++j) {
    int node = nodeBase + j;
    out[node * D + lane] = acc[j];
  }
}

extern "C" void kernel_launch(void* const* d_in, const int* in_sizes, int n_in,
                              void* d_out, int out_size, void* d_ws, size_t ws_size,
                              hipStream_t stream) {
  const float* x = (const float*)d_in[0];
  const int* ei = (const int*)d_in[1];
  BranchParams P;
  for (int i = 0; i < 5; ++i) {
    P.W[i] = (const float*)d_in[2 + 4 * i];
    P.b[i] = (const float*)d_in[3 + 4 * i];
    P.wa[i] = (const float*)d_in[4 + 4 * i];
    P.ba[i] = (const float*)d_in[5 + 4 * i];
  }
  float* axs = (float*)d_ws;
  float* aaxs = axs + (size_t)N * D;
  float* deg = aaxs + (size_t)N * D;

  // zero accumulators (harness does not re-poison between replays)
  size_t zero_bytes = ((size_t)N * D * 2 + (size_t)N) * sizeof(float);
  hipMemsetAsync(d_ws, 0, zero_bytes, stream);

  const int scatter_blocks = (E * 64) / 256;  // 200000, exact
  hipLaunchKernelGGL(k_scatter1, dim3(scatter_blocks), dim3(256), 0, stream,
                     ei, x, axs, deg);
  hipLaunchKernelGGL(k_scatter2, dim3(scatter_blocks), dim3(256), 0, stream,
                     ei, axs, deg, aaxs);
  hipLaunchKernelGGL(k_branch, dim3(N / 16), dim3(256), 0, stream,
                     x, axs, aaxs, deg, P, (float*)d_out);
}

// Round 2
// 273.725 us; speedup vs baseline: 1.7724x; 1.7724x over previous
//
#include <hip/hip_runtime.h>
#include <hip/hip_bf16.h>

constexpr int N = 50000;
constexpr int E = 800000;
constexpr int D = 64;

struct BranchParams {
  const float* W[5];
  const float* b[5];
  const float* wa[5];
  const float* ba[5];
};

// ---- CSR build ----------------------------------------------------------

// deg_i[dst] += 1 for each edge (int atomics, L2-side, fast).
__global__ __launch_bounds__(256) void k_count(const int* __restrict__ ei,
                                               int* __restrict__ deg_i) {
  int t = blockIdx.x * 256 + threadIdx.x;  // grid exact: E/256 blocks
  atomicAdd(&deg_i[ei[E + t]], 1);
}

// Single-block exclusive scan of deg_i -> pos (fill cursors), plus invdeg.
// After k_fill mutates pos, pos[i] == off[i+1]; start(i) = i ? pos[i-1] : 0.
__global__ __launch_bounds__(1024) void k_scan(const int* __restrict__ deg_i,
                                               int* __restrict__ pos,
                                               float* __restrict__ invdeg) {
  __shared__ int wsum[16];
  __shared__ int carry_s;
  if (threadIdx.x == 0) carry_s = 0;
  __syncthreads();
  const int lane = threadIdx.x & 63;
  const int wid = threadIdx.x >> 6;
  for (int base = 0; base < N; base += 4096) {
    int i0 = base + threadIdx.x * 4;
    int v0 = 0, v1 = 0, v2 = 0, v3 = 0;
    if (i0 + 3 < N) {
      int4 v = *(const int4*)&deg_i[i0];
      v0 = v.x; v1 = v.y; v2 = v.z; v3 = v.w;
    } else {
      if (i0 + 0 < N) v0 = deg_i[i0 + 0];
      if (i0 + 1 < N) v1 = deg_i[i0 + 1];
      if (i0 + 2 < N) v2 = deg_i[i0 + 2];
      if (i0 + 3 < N) v3 = deg_i[i0 + 3];
    }
    int tsum = v0 + v1 + v2 + v3;
    int s = tsum;
#pragma unroll
    for (int o = 1; o < 64; o <<= 1) {
      int t = __shfl_up(s, o);
      if (lane >= o) s += t;
    }
    if (lane == 63) wsum[wid] = s;
    __syncthreads();
    int pre = carry_s;
#pragma unroll
    for (int w = 0; w < 16; ++w) pre += (w < wid) ? wsum[w] : 0;
    int excl = pre + s - tsum;
    if (i0 + 0 < N) { pos[i0 + 0] = excl;                invdeg[i0 + 0] = 1.0f / fmaxf((float)v0, 1.0f); }
    if (i0 + 1 < N) { pos[i0 + 1] = excl + v0;           invdeg[i0 + 1] = 1.0f / fmaxf((float)v1, 1.0f); }
    if (i0 + 2 < N) { pos[i0 + 2] = excl + v0 + v1;      invdeg[i0 + 2] = 1.0f / fmaxf((float)v2, 1.0f); }
    if (i0 + 3 < N) { pos[i0 + 3] = excl + v0 + v1 + v2; invdeg[i0 + 3] = 1.0f / fmaxf((float)v3, 1.0f); }
    __syncthreads();
    if (threadIdx.x == 1023) carry_s = pre + s;  // total through this chunk
    __syncthreads();
  }
}

// Scatter src indices into dst-sorted order.
__global__ __launch_bounds__(256) void k_fill(const int* __restrict__ ei,
                                              int* __restrict__ pos,
                                              int* __restrict__ srcs) {
  int t = blockIdx.x * 256 + threadIdx.x;
  int dst = ei[E + t];
  int p = atomicAdd(&pos[dst], 1);
  srcs[p] = ei[t];
}

// ---- mean aggregation: out[node] = invdeg[node] * sum_{e in CSR} in[srcs[e]]
// One wave per node, lane = feature. Rows already include upstream scaling.
__global__ __launch_bounds__(256) void k_agg(
    const int* __restrict__ pos, const int* __restrict__ srcs,
    const float* __restrict__ in, const float* __restrict__ invdeg,
    float* __restrict__ outb) {
  int node = blockIdx.x * 4 + (threadIdx.x >> 6);
  int lane = threadIdx.x & 63;
  int start = (node == 0) ? 0 : pos[node - 1];
  int end = pos[node];
  float s = 0.f;
  int e = start;
  for (; e + 4 <= end; e += 4) {  // 4 gathers in flight
    int i0 = srcs[e], i1 = srcs[e + 1], i2 = srcs[e + 2], i3 = srcs[e + 3];
    float a = in[i0 * D + lane], b = in[i1 * D + lane];
    float c = in[i2 * D + lane], d = in[i3 * D + lane];
    s += (a + b) + (c + d);
  }
  for (; e < end; ++e) s += in[srcs[e] * D + lane];
  outb[node * D + lane] = s * invdeg[node];
}

// ---- fused per-node 5-branch GEMV + ReLU + sigmoid gate + gated sum -----
__global__ __launch_bounds__(256) void k_branch(
    const float* __restrict__ x, const float* __restrict__ ax,
    const float* __restrict__ aax, BranchParams P, float* __restrict__ out) {
  __shared__ float Wlds[D * D];
  const int lane = threadIdx.x & 63;
  const int wid = threadIdx.x >> 6;
  const int nodeBase = blockIdx.x * 16 + wid * 4;  // N = 3125*16, no tail

  float px[4], pax[4], paax[4], acc[4];
#pragma unroll
  for (int j = 0; j < 4; ++j) {
    int node = nodeBase + j;
    px[j] = x[node * D + lane];
    pax[j] = ax[node * D + lane];
    paax[j] = aax[node * D + lane];
    acc[j] = 0.0f;
  }

  for (int br = 0; br < 5; ++br) {
    __syncthreads();
#pragma unroll
    for (int i = threadIdx.x; i < D * D / 4; i += 256)
      ((float4*)Wlds)[i] = ((const float4*)P.W[br])[i];
    __syncthreads();
    const float bv = P.b[br][lane];
    const float wav = P.wa[br][lane];
    const float bav = P.ba[br][0];
#pragma unroll
    for (int j = 0; j < 4; ++j) {
      float p;
      switch (br) {
        case 0: p = px[j] - pax[j]; break;                   // hp
        case 1: p = pax[j]; break;                           // lp
        case 2: p = px[j]; break;                            // i
        case 3: p = px[j] - 2.0f * pax[j] + paax[j]; break;  // hp2
        default: p = paax[j]; break;                         // lp2
      }
      float h = bv;
#pragma unroll
      for (int k = 0; k < D; ++k) {
        float pk = __int_as_float(__builtin_amdgcn_readlane(__float_as_int(p), k));
        h = fmaf(pk, Wlds[k * D + lane], h);
      }
      h = fmaxf(h, 0.0f);
      float g = h * wav;
#pragma unroll
      for (int o = 32; o > 0; o >>= 1) g += __shfl_xor(g, o);
      float alpha = 1.0f / (1.0f + __expf(-(g + bav)));
      acc[j] = fmaf(alpha, h, acc[j]);
    }
  }
#pragma unroll
  for (int j = 0; j < 4; ++j) {
    int node = nodeBase + j;
    out[node * D + lane] = acc[j];
  }
}

extern "C" void kernel_launch(void* const* d_in, const int* in_sizes, int n_in,
                              void* d_out, int out_size, void* d_ws, size_t ws_size,
                              hipStream_t stream) {
  const float* x = (const float*)d_in[0];
  const int* ei = (const int*)d_in[1];
  BranchParams P;
  for (int i = 0; i < 5; ++i) {
    P.W[i] = (const float*)d_in[2 + 4 * i];
    P.b[i] = (const float*)d_in[3 + 4 * i];
    P.wa[i] = (const float*)d_in[4 + 4 * i];
    P.ba[i] = (const float*)d_in[5 + 4 * i];
  }

  // workspace layout
  float* ax = (float*)d_ws;                 // N*D
  float* aax = ax + (size_t)N * D;          // N*D
  float* invdeg = aax + (size_t)N * D;      // N
  int* deg_i = (int*)(invdeg + N);          // N
  int* pos = deg_i + N;                     // N
  int* srcs = pos + N;                      // E

  // only the histogram needs zeroing; everything else is fully overwritten
  hipMemsetAsync(deg_i, 0, (size_t)N * sizeof(int), stream);

  const int eblocks = E / 256;  // 3125, exact
  hipLaunchKernelGGL(k_count, dim3(eblocks), dim3(256), 0, stream, ei, deg_i);
  hipLaunchKernelGGL(k_scan, dim3(1), dim3(1024), 0, stream, deg_i, pos, invdeg);
  hipLaunchKernelGGL(k_fill, dim3(eblocks), dim3(256), 0, stream, ei, pos, srcs);
  hipLaunchKernelGGL(k_agg, dim3(N / 4), dim3(256), 0, stream, pos, srcs, x, invdeg, ax);
  hipLaunchKernelGGL(k_agg, dim3(N / 4), dim3(256), 0, stream, pos, srcs, ax, invdeg, aax);
  hipLaunchKernelGGL(k_branch, dim3(N / 16), dim3(256), 0, stream, x, ax, aax, P,
                     (float*)d_out);
}

// Round 3
// 204.750 us; speedup vs baseline: 2.3695x; 1.3369x over previous
//
#include <hip/hip_runtime.h>
#include <hip/hip_bf16.h>

constexpr int N = 50000;
constexpr int E = 800000;
constexpr int D = 64;

typedef __attribute__((ext_vector_type(8))) short s8v;    // 8 bf16 (4 VGPRs)
typedef __attribute__((ext_vector_type(4))) float f32x4;  // mfma accumulator

struct BranchParams {
  const float* W[5];
  const float* b[5];
  const float* wa[5];
  const float* ba[5];
};

__device__ inline short f2bf(float f) {  // RNE float->bf16 bits
  unsigned u = __float_as_uint(f);
  u += 0x7fff + ((u >> 16) & 1);
  return (short)(u >> 16);
}

// ---- CSR build ----------------------------------------------------------

__global__ __launch_bounds__(256) void k_count(const int* __restrict__ ei,
                                               int* __restrict__ deg_i) {
  int t = blockIdx.x * 256 + threadIdx.x;
  atomicAdd(&deg_i[ei[E + t]], 1);
}

__global__ __launch_bounds__(1024) void k_scan(const int* __restrict__ deg_i,
                                               int* __restrict__ pos,
                                               float* __restrict__ invdeg) {
  __shared__ int wsum[16];
  __shared__ int carry_s;
  if (threadIdx.x == 0) carry_s = 0;
  __syncthreads();
  const int lane = threadIdx.x & 63;
  const int wid = threadIdx.x >> 6;
  for (int base = 0; base < N; base += 4096) {
    int i0 = base + threadIdx.x * 4;
    int v0 = 0, v1 = 0, v2 = 0, v3 = 0;
    if (i0 + 3 < N) {
      int4 v = *(const int4*)&deg_i[i0];
      v0 = v.x; v1 = v.y; v2 = v.z; v3 = v.w;
    } else {
      if (i0 + 0 < N) v0 = deg_i[i0 + 0];
      if (i0 + 1 < N) v1 = deg_i[i0 + 1];
      if (i0 + 2 < N) v2 = deg_i[i0 + 2];
      if (i0 + 3 < N) v3 = deg_i[i0 + 3];
    }
    int tsum = v0 + v1 + v2 + v3;
    int s = tsum;
#pragma unroll
    for (int o = 1; o < 64; o <<= 1) {
      int t = __shfl_up(s, o);
      if (lane >= o) s += t;
    }
    if (lane == 63) wsum[wid] = s;
    __syncthreads();
    int pre = carry_s;
#pragma unroll
    for (int w = 0; w < 16; ++w) pre += (w < wid) ? wsum[w] : 0;
    int excl = pre + s - tsum;
    if (i0 + 0 < N) { pos[i0 + 0] = excl;                invdeg[i0 + 0] = 1.0f / fmaxf((float)v0, 1.0f); }
    if (i0 + 1 < N) { pos[i0 + 1] = excl + v0;           invdeg[i0 + 1] = 1.0f / fmaxf((float)v1, 1.0f); }
    if (i0 + 2 < N) { pos[i0 + 2] = excl + v0 + v1;      invdeg[i0 + 2] = 1.0f / fmaxf((float)v2, 1.0f); }
    if (i0 + 3 < N) { pos[i0 + 3] = excl + v0 + v1 + v2; invdeg[i0 + 3] = 1.0f / fmaxf((float)v3, 1.0f); }
    __syncthreads();
    if (threadIdx.x == 1023) carry_s = pre + s;
    __syncthreads();
  }
}

__global__ __launch_bounds__(256) void k_fill(const int* __restrict__ ei,
                                              int* __restrict__ pos,
                                              int* __restrict__ srcs) {
  int t = blockIdx.x * 256 + threadIdx.x;
  int dst = ei[E + t];
  int p = atomicAdd(&pos[dst], 1);
  srcs[p] = ei[t];
}

// ---- mean aggregation (CSR gather) --------------------------------------
__global__ __launch_bounds__(256) void k_agg(
    const int* __restrict__ pos, const int* __restrict__ srcs,
    const float* __restrict__ in, const float* __restrict__ invdeg,
    float* __restrict__ outb) {
  int node = blockIdx.x * 4 + (threadIdx.x >> 6);
  int lane = threadIdx.x & 63;
  int start = (node == 0) ? 0 : pos[node - 1];
  int end = pos[node];
  float s = 0.f;
  int e = start;
  for (; e + 4 <= end; e += 4) {
    int i0 = srcs[e], i1 = srcs[e + 1], i2 = srcs[e + 2], i3 = srcs[e + 3];
    float a = in[i0 * D + lane], b = in[i1 * D + lane];
    float c = in[i2 * D + lane], d = in[i3 * D + lane];
    s += (a + b) + (c + d);
  }
  for (; e < end; ++e) s += in[srcs[e] * D + lane];
  outb[node * D + lane] = s * invdeg[node];
}

// ---- W -> bf16 MFMA B-fragment order ------------------------------------
// frag id = (br*4 + ct)*2 + kk; lane holds B[k][col], col = ct*16 + (lane&15),
// k = kk*32 + (lane>>4)*8 + j, j = 0..7.
__global__ __launch_bounds__(64) void k_prepw(BranchParams P, short* __restrict__ wf) {
  int bfrag = blockIdx.x;
  int br = bfrag >> 3, ct = (bfrag >> 1) & 3, kk = bfrag & 1;
  int lane = threadIdx.x;
  const float* W = P.W[br];
  int col = ct * 16 + (lane & 15);
  int k0 = kk * 32 + (lane >> 4) * 8;
  s8v v;
#pragma unroll
  for (int j = 0; j < 8; ++j) v[j] = f2bf(W[(k0 + j) * D + col]);
  ((s8v*)wf)[bfrag * 64 + lane] = v;
}

// ---- fused 5-branch MFMA GEMM + ReLU + sigmoid gate + gated sum ---------
// One wave per 16 nodes; no LDS.
__global__ __launch_bounds__(256) void k_branch(
    const float* __restrict__ x, const float* __restrict__ ax,
    const float* __restrict__ aax, BranchParams P,
    const short* __restrict__ wf, float* __restrict__ out) {
  const int lane = threadIdx.x & 63;
  const int wid = threadIdx.x >> 6;
  const int base = blockIdx.x * 64 + wid * 16;
  if (base >= N) return;
  const int l16 = lane & 15;   // A-row on load; C-col on output
  const int kg = lane >> 4;    // k-group on load; C-row-group on output

  // Per-lane inputs: node (base+l16), features kk*32 + kg*8 + {0..7}
  float px[16], pax[16], paax[16];
  const float4* xr = (const float4*)&x[(base + l16) * D];
  const float4* ar = (const float4*)&ax[(base + l16) * D];
  const float4* br2 = (const float4*)&aax[(base + l16) * D];
#pragma unroll
  for (int kk = 0; kk < 2; ++kk) {
#pragma unroll
    for (int q = 0; q < 2; ++q) {
      float4 vx = xr[kk * 8 + kg * 2 + q];
      float4 va = ar[kk * 8 + kg * 2 + q];
      float4 vb = br2[kk * 8 + kg * 2 + q];
      int o = kk * 8 + q * 4;
      px[o + 0] = vx.x; px[o + 1] = vx.y; px[o + 2] = vx.z; px[o + 3] = vx.w;
      pax[o + 0] = va.x; pax[o + 1] = va.y; pax[o + 2] = va.z; pax[o + 3] = va.w;
      paax[o + 0] = vb.x; paax[o + 1] = vb.y; paax[o + 2] = vb.z; paax[o + 3] = vb.w;
    }
  }

  f32x4 oacc[4] = {{0.f, 0.f, 0.f, 0.f}, {0.f, 0.f, 0.f, 0.f},
                   {0.f, 0.f, 0.f, 0.f}, {0.f, 0.f, 0.f, 0.f}};
  const s8v* wf8 = (const s8v*)wf;

#pragma unroll
  for (int brn = 0; brn < 5; ++brn) {
    // A fragments for this branch (fp32 -> bf16)
    s8v afr[2];
#pragma unroll
    for (int kk = 0; kk < 2; ++kk) {
#pragma unroll
      for (int j = 0; j < 8; ++j) {
        int o = kk * 8 + j;
        float p;
        switch (brn) {
          case 0: p = px[o] - pax[o]; break;                      // hp
          case 1: p = pax[o]; break;                              // lp
          case 2: p = px[o]; break;                               // i
          case 3: p = px[o] - 2.0f * pax[o] + paax[o]; break;     // hp2
          default: p = paax[o]; break;                            // lp2
        }
        afr[kk][j] = f2bf(p);
      }
    }
    f32x4 acc[4];
#pragma unroll
    for (int ct = 0; ct < 4; ++ct) {
      f32x4 a = {0.f, 0.f, 0.f, 0.f};
      a = __builtin_amdgcn_mfma_f32_16x16x32_bf16(
          afr[0], wf8[((brn * 4 + ct) * 2 + 0) * 64 + lane], a, 0, 0, 0);
      a = __builtin_amdgcn_mfma_f32_16x16x32_bf16(
          afr[1], wf8[((brn * 4 + ct) * 2 + 1) * 64 + lane], a, 0, 0, 0);
      acc[ct] = a;
    }
    float bcol[4], wacol[4];
#pragma unroll
    for (int ct = 0; ct < 4; ++ct) {
      bcol[ct] = P.b[brn][ct * 16 + l16];
      wacol[ct] = P.wa[brn][ct * 16 + l16];
    }
    const float bav = P.ba[brn][0];
    // C/D layout: col = lane&15 (+16*ct), row = kg*4 + i
#pragma unroll
    for (int i = 0; i < 4; ++i) {
      float h[4], g = 0.f;
#pragma unroll
      for (int ct = 0; ct < 4; ++ct) {
        h[ct] = fmaxf(acc[ct][i] + bcol[ct], 0.f);
        g = fmaf(h[ct], wacol[ct], g);
      }
#pragma unroll
      for (int o = 1; o < 16; o <<= 1) g += __shfl_xor(g, o);  // sum over cols
      float alpha = 1.0f / (1.0f + __expf(-(g + bav)));
#pragma unroll
      for (int ct = 0; ct < 4; ++ct) oacc[ct][i] = fmaf(alpha, h[ct], oacc[ct][i]);
    }
  }
#pragma unroll
  for (int ct = 0; ct < 4; ++ct)
#pragma unroll
    for (int i = 0; i < 4; ++i)
      out[(base + kg * 4 + i) * D + ct * 16 + l16] = oacc[ct][i];
}

extern "C" void kernel_launch(void* const* d_in, const int* in_sizes, int n_in,
                              void* d_out, int out_size, void* d_ws, size_t ws_size,
                              hipStream_t stream) {
  const float* x = (const float*)d_in[0];
  const int* ei = (const int*)d_in[1];
  BranchParams P;
  for (int i = 0; i < 5; ++i) {
    P.W[i] = (const float*)d_in[2 + 4 * i];
    P.b[i] = (const float*)d_in[3 + 4 * i];
    P.wa[i] = (const float*)d_in[4 + 4 * i];
    P.ba[i] = (const float*)d_in[5 + 4 * i];
  }

  float* ax = (float*)d_ws;                 // N*D
  float* aax = ax + (size_t)N * D;          // N*D
  float* invdeg = aax + (size_t)N * D;      // N
  int* deg_i = (int*)(invdeg + N);          // N
  int* pos = deg_i + N;                     // N
  int* srcs = pos + N;                      // E
  short* wf = (short*)(srcs + E);           // 40 frags * 512 bf16

  hipMemsetAsync(deg_i, 0, (size_t)N * sizeof(int), stream);

  const int eblocks = E / 256;  // 3125, exact
  hipLaunchKernelGGL(k_count, dim3(eblocks), dim3(256), 0, stream, ei, deg_i);
  hipLaunchKernelGGL(k_scan, dim3(1), dim3(1024), 0, stream, deg_i, pos, invdeg);
  hipLaunchKernelGGL(k_fill, dim3(eblocks), dim3(256), 0, stream, ei, pos, srcs);
  hipLaunchKernelGGL(k_prepw, dim3(40), dim3(64), 0, stream, P, wf);
  hipLaunchKernelGGL(k_agg, dim3(N / 4), dim3(256), 0, stream, pos, srcs, x, invdeg, ax);
  hipLaunchKernelGGL(k_agg, dim3(N / 4), dim3(256), 0, stream, pos, srcs, ax, invdeg, aax);
  hipLaunchKernelGGL(k_branch, dim3((N + 63) / 64), dim3(256), 0, stream,
                     x, ax, aax, P, wf, (float*)d_out);
}

// Round 4
// 188.596 us; speedup vs baseline: 2.5724x; 1.0857x over previous
//
#include <hip/hip_runtime.h>
#include <hip/hip_bf16.h>

constexpr int N = 50000;
constexpr int E = 800000;
constexpr int D = 64;

typedef __attribute__((ext_vector_type(8))) short s8v;    // 8 bf16 (4 VGPRs)
typedef __attribute__((ext_vector_type(4))) float f32x4;  // mfma accumulator

struct BranchParams {
  const float* W[5];
  const float* b[5];
  const float* wa[5];
  const float* ba[5];
};

__device__ inline short f2bf(float f) {  // RNE float->bf16 bits
  unsigned u = __float_as_uint(f);
  u += 0x7fff + ((u >> 16) & 1);
  return (short)(u >> 16);
}
__device__ inline float bflo(unsigned v) { return __uint_as_float(v << 16); }
__device__ inline float bfhi(unsigned v) { return __uint_as_float(v & 0xffff0000u); }
__device__ inline float bfs(short s) {
  return __uint_as_float(((unsigned)(unsigned short)s) << 16);
}
__device__ inline unsigned pack2(float lo, float hi) {
  return ((unsigned)(unsigned short)f2bf(lo)) |
         (((unsigned)(unsigned short)f2bf(hi)) << 16);
}

// ---- x (fp32) -> bf16 packed rows ---------------------------------------
__global__ __launch_bounds__(256) void k_prepx(const float* __restrict__ x,
                                               uint* __restrict__ xbf) {
  int t = blockIdx.x * 256 + threadIdx.x;
  if (t >= N * D / 8) return;
  const float4* p = (const float4*)(x + (size_t)t * 8);
  float4 a = p[0], b = p[1];
  uint4 o;
  o.x = pack2(a.x, a.y);
  o.y = pack2(a.z, a.w);
  o.z = pack2(b.x, b.y);
  o.w = pack2(b.z, b.w);
  ((uint4*)xbf)[t] = o;
}

// ---- CSR build ----------------------------------------------------------
__global__ __launch_bounds__(256) void k_count(const int* __restrict__ ei,
                                               int* __restrict__ deg_i) {
  int t = blockIdx.x * 256 + threadIdx.x;
  atomicAdd(&deg_i[ei[E + t]], 1);
}

__global__ __launch_bounds__(1024) void k_scan(const int* __restrict__ deg_i,
                                               int* __restrict__ pos,
                                               float* __restrict__ invdeg) {
  __shared__ int wsum[16];
  __shared__ int carry_s;
  if (threadIdx.x == 0) carry_s = 0;
  __syncthreads();
  const int lane = threadIdx.x & 63;
  const int wid = threadIdx.x >> 6;
  for (int base = 0; base < N; base += 4096) {
    int i0 = base + threadIdx.x * 4;
    int v0 = 0, v1 = 0, v2 = 0, v3 = 0;
    if (i0 + 3 < N) {
      int4 v = *(const int4*)&deg_i[i0];
      v0 = v.x; v1 = v.y; v2 = v.z; v3 = v.w;
    } else {
      if (i0 + 0 < N) v0 = deg_i[i0 + 0];
      if (i0 + 1 < N) v1 = deg_i[i0 + 1];
      if (i0 + 2 < N) v2 = deg_i[i0 + 2];
      if (i0 + 3 < N) v3 = deg_i[i0 + 3];
    }
    int tsum = v0 + v1 + v2 + v3;
    int s = tsum;
#pragma unroll
    for (int o = 1; o < 64; o <<= 1) {
      int t = __shfl_up(s, o);
      if (lane >= o) s += t;
    }
    if (lane == 63) wsum[wid] = s;
    __syncthreads();
    int pre = carry_s;
#pragma unroll
    for (int w = 0; w < 16; ++w) pre += (w < wid) ? wsum[w] : 0;
    int excl = pre + s - tsum;
    if (i0 + 0 < N) { pos[i0 + 0] = excl;                invdeg[i0 + 0] = 1.0f / fmaxf((float)v0, 1.0f); }
    if (i0 + 1 < N) { pos[i0 + 1] = excl + v0;           invdeg[i0 + 1] = 1.0f / fmaxf((float)v1, 1.0f); }
    if (i0 + 2 < N) { pos[i0 + 2] = excl + v0 + v1;      invdeg[i0 + 2] = 1.0f / fmaxf((float)v2, 1.0f); }
    if (i0 + 3 < N) { pos[i0 + 3] = excl + v0 + v1 + v2; invdeg[i0 + 3] = 1.0f / fmaxf((float)v3, 1.0f); }
    __syncthreads();
    if (threadIdx.x == 1023) carry_s = pre + s;
    __syncthreads();
  }
}

__global__ __launch_bounds__(256) void k_fill(const int* __restrict__ ei,
                                              int* __restrict__ pos,
                                              ushort* __restrict__ srcs) {
  int t = blockIdx.x * 256 + threadIdx.x;
  int dst = ei[E + t];
  int p = atomicAdd(&pos[dst], 1);
  srcs[p] = (ushort)ei[t];
}

// ---- mean aggregation (CSR gather, bf16 rows, 2 edges per instr) --------
// inbf/outbf: packed rows of 32 uints (2 bf16 features per uint).
__global__ __launch_bounds__(256) void k_agg(
    const int* __restrict__ pos, const ushort* __restrict__ srcs,
    const uint* __restrict__ inbf, const float* __restrict__ invdeg,
    uint* __restrict__ outbf) {
  int node = blockIdx.x * 4 + (threadIdx.x >> 6);
  int lane = threadIdx.x & 63;
  int half = lane >> 5;  // edge parity handled by this half-wave
  int fp = lane & 31;    // feature-pair index
  int start = (node == 0) ? 0 : pos[node - 1];
  int end = pos[node];
  int m = end - start;
  int np = m >> 1;
  float sx = 0.f, sy = 0.f;
  int e = start + half;
  int i = 0;
  for (; i + 2 <= np; i += 2, e += 4) {  // 4 edges in flight
    int s0 = srcs[e], s1 = srcs[e + 2];
    uint v0 = inbf[s0 * 32 + fp];
    uint v1 = inbf[s1 * 32 + fp];
    sx += bflo(v0); sy += bfhi(v0);
    sx += bflo(v1); sy += bfhi(v1);
  }
  if (i < np) {
    int s0 = srcs[e];
    uint v0 = inbf[s0 * 32 + fp];
    sx += bflo(v0); sy += bfhi(v0);
  }
  if ((m & 1) && half == 0) {  // odd tail: half 0 only
    int s0 = srcs[end - 1];
    uint v0 = inbf[s0 * 32 + fp];
    sx += bflo(v0); sy += bfhi(v0);
  }
  sx += __shfl_xor(sx, 32);
  sy += __shfl_xor(sy, 32);
  if (half == 0) {
    float inv = invdeg[node];
    outbf[node * 32 + fp] = pack2(sx * inv, sy * inv);
  }
}

// ---- W -> bf16 MFMA B-fragment order ------------------------------------
__global__ __launch_bounds__(64) void k_prepw(BranchParams P, short* __restrict__ wf) {
  int bfrag = blockIdx.x;
  int br = bfrag >> 3, ct = (bfrag >> 1) & 3, kk = bfrag & 1;
  int lane = threadIdx.x;
  const float* W = P.W[br];
  int col = ct * 16 + (lane & 15);
  int k0 = kk * 32 + (lane >> 4) * 8;
  s8v v;
#pragma unroll
  for (int j = 0; j < 8; ++j) v[j] = f2bf(W[(k0 + j) * D + col]);
  ((s8v*)wf)[bfrag * 64 + lane] = v;
}

// ---- fused 5-branch MFMA GEMM + ReLU + sigmoid gate + gated sum ---------
__global__ __launch_bounds__(256) void k_branch(
    const ushort* __restrict__ xbf, const ushort* __restrict__ axbf,
    const ushort* __restrict__ aaxbf, BranchParams P,
    const short* __restrict__ wf, float* __restrict__ out) {
  const int lane = threadIdx.x & 63;
  const int wid = threadIdx.x >> 6;
  const int base = blockIdx.x * 64 + wid * 16;
  if (base >= N) return;  // 50000 = 3125 waves exactly; no partial waves
  const int l16 = lane & 15;
  const int kg = lane >> 4;

  // raw bf16 fragments straight from memory (rows of 8 s8v groups)
  const s8v* xr = (const s8v*)(xbf + (size_t)(base + l16) * D);
  const s8v* ar = (const s8v*)(axbf + (size_t)(base + l16) * D);
  const s8v* cr = (const s8v*)(aaxbf + (size_t)(base + l16) * D);
  s8v xv[2], av[2], bv[2];
  xv[0] = xr[kg]; xv[1] = xr[4 + kg];  // group index = kk*4 + kg
  av[0] = ar[kg]; av[1] = ar[4 + kg];
  bv[0] = cr[kg]; bv[1] = cr[4 + kg];

  // hp = x - ax ; hp2 = x - 2 ax + aax (float math, repack to bf16)
  s8v hpv[2], hp2v[2];
#pragma unroll
  for (int kk = 0; kk < 2; ++kk) {
#pragma unroll
    for (int j = 0; j < 8; ++j) {
      float fx = bfs(xv[kk][j]), fa = bfs(av[kk][j]), fb = bfs(bv[kk][j]);
      hpv[kk][j] = f2bf(fx - fa);
      hp2v[kk][j] = f2bf(fx - 2.0f * fa + fb);
    }
  }

  f32x4 oacc[4] = {{0.f, 0.f, 0.f, 0.f}, {0.f, 0.f, 0.f, 0.f},
                   {0.f, 0.f, 0.f, 0.f}, {0.f, 0.f, 0.f, 0.f}};
  const s8v* wf8 = (const s8v*)wf;

#pragma unroll
  for (int brn = 0; brn < 5; ++brn) {
    s8v a0, a1;
    switch (brn) {
      case 0: a0 = hpv[0]; a1 = hpv[1]; break;   // hp
      case 1: a0 = av[0]; a1 = av[1]; break;     // lp
      case 2: a0 = xv[0]; a1 = xv[1]; break;     // i
      case 3: a0 = hp2v[0]; a1 = hp2v[1]; break; // hp2
      default: a0 = bv[0]; a1 = bv[1]; break;    // lp2
    }
    f32x4 acc[4];
#pragma unroll
    for (int ct = 0; ct < 4; ++ct) {
      f32x4 a = {0.f, 0.f, 0.f, 0.f};
      a = __builtin_amdgcn_mfma_f32_16x16x32_bf16(
          a0, wf8[((brn * 4 + ct) * 2 + 0) * 64 + lane], a, 0, 0, 0);
      a = __builtin_amdgcn_mfma_f32_16x16x32_bf16(
          a1, wf8[((brn * 4 + ct) * 2 + 1) * 64 + lane], a, 0, 0, 0);
      acc[ct] = a;
    }
    float bcol[4], wacol[4];
#pragma unroll
    for (int ct = 0; ct < 4; ++ct) {
      bcol[ct] = P.b[brn][ct * 16 + l16];
      wacol[ct] = P.wa[brn][ct * 16 + l16];
    }
    const float bav = P.ba[brn][0];
    // C/D layout: col = lane&15 (+16*ct), row = kg*4 + i
#pragma unroll
    for (int i = 0; i < 4; ++i) {
      float h[4], g = 0.f;
#pragma unroll
      for (int ct = 0; ct < 4; ++ct) {
        h[ct] = fmaxf(acc[ct][i] + bcol[ct], 0.f);
        g = fmaf(h[ct], wacol[ct], g);
      }
#pragma unroll
      for (int o = 1; o < 16; o <<= 1) g += __shfl_xor(g, o);  // sum over cols
      float alpha = 1.0f / (1.0f + __expf(-(g + bav)));
#pragma unroll
      for (int ct = 0; ct < 4; ++ct) oacc[ct][i] = fmaf(alpha, h[ct], oacc[ct][i]);
    }
  }
#pragma unroll
  for (int ct = 0; ct < 4; ++ct)
#pragma unroll
    for (int i = 0; i < 4; ++i)
      out[(size_t)(base + kg * 4 + i) * D + ct * 16 + l16] = oacc[ct][i];
}

extern "C" void kernel_launch(void* const* d_in, const int* in_sizes, int n_in,
                              void* d_out, int out_size, void* d_ws, size_t ws_size,
                              hipStream_t stream) {
  const float* x = (const float*)d_in[0];
  const int* ei = (const int*)d_in[1];
  BranchParams P;
  for (int i = 0; i < 5; ++i) {
    P.W[i] = (const float*)d_in[2 + 4 * i];
    P.b[i] = (const float*)d_in[3 + 4 * i];
    P.wa[i] = (const float*)d_in[4 + 4 * i];
    P.ba[i] = (const float*)d_in[5 + 4 * i];
  }

  // workspace layout (bytes): xbf 6.4M | axbf 6.4M | aaxbf 6.4M | invdeg 200K
  //                           | deg_i 200K | pos 200K | srcs(u16) 1.6M | wf 40K
  char* w = (char*)d_ws;
  uint* xbf = (uint*)w;                          w += (size_t)N * D * 2;
  uint* axbf = (uint*)w;                         w += (size_t)N * D * 2;
  uint* aaxbf = (uint*)w;                        w += (size_t)N * D * 2;
  float* invdeg = (float*)w;                     w += (size_t)N * 4;
  int* deg_i = (int*)w;                          w += (size_t)N * 4;
  int* pos = (int*)w;                            w += (size_t)N * 4;
  ushort* srcs = (ushort*)w;                     w += (size_t)E * 2;
  short* wf = (short*)w;

  hipMemsetAsync(deg_i, 0, (size_t)N * sizeof(int), stream);

  const int eblocks = E / 256;  // 3125, exact
  hipLaunchKernelGGL(k_prepx, dim3((N * D / 8 + 255) / 256), dim3(256), 0, stream, x, xbf);
  hipLaunchKernelGGL(k_count, dim3(eblocks), dim3(256), 0, stream, ei, deg_i);
  hipLaunchKernelGGL(k_scan, dim3(1), dim3(1024), 0, stream, deg_i, pos, invdeg);
  hipLaunchKernelGGL(k_fill, dim3(eblocks), dim3(256), 0, stream, ei, pos, srcs);
  hipLaunchKernelGGL(k_prepw, dim3(40), dim3(64), 0, stream, P, wf);
  hipLaunchKernelGGL(k_agg, dim3(N / 4), dim3(256), 0, stream, pos, srcs, xbf, invdeg, axbf);
  hipLaunchKernelGGL(k_agg, dim3(N / 4), dim3(256), 0, stream, pos, srcs, axbf, invdeg, aaxbf);
  hipLaunchKernelGGL(k_branch, dim3((N + 63) / 64), dim3(256), 0, stream,
                     (const ushort*)xbf, (const ushort*)axbf, (const ushort*)aaxbf,
                     P, wf, (float*)d_out);
}

// Round 5
// 178.355 us; speedup vs baseline: 2.7201x; 1.0574x over previous
//
#include <hip/hip_runtime.h>
#include <hip/hip_bf16.h>

constexpr int N = 50000;
constexpr int E = 800000;
constexpr int D = 64;
constexpr int GSZ = N / 8;                    // 6250 nodes per XCD group
constexpr int EBLK = E / 256;                 // 3125 edge chunks
constexpr int CNT_BLOCKS = EBLK * 8;          // count replicas
constexpr int PREPX_BLOCKS = (N * D / 8 + 255) / 256;  // 1563

typedef __attribute__((ext_vector_type(8))) short s8v;    // 8 bf16 (4 VGPRs)
typedef __attribute__((ext_vector_type(4))) float f32x4;  // mfma accumulator

struct BranchParams {
  const float* W[5];
  const float* b[5];
  const float* wa[5];
  const float* ba[5];
};

__device__ inline short f2bf(float f) {  // RNE float->bf16 bits
  unsigned u = __float_as_uint(f);
  u += 0x7fff + ((u >> 16) & 1);
  return (short)(u >> 16);
}
__device__ inline float bflo(unsigned v) { return __uint_as_float(v << 16); }
__device__ inline float bfhi(unsigned v) { return __uint_as_float(v & 0xffff0000u); }
__device__ inline float bfs(short s) {
  return __uint_as_float(((unsigned)(unsigned short)s) << 16);
}
__device__ inline unsigned pack2(float lo, float hi) {
  return ((unsigned)(unsigned short)f2bf(lo)) |
         (((unsigned)(unsigned short)f2bf(hi)) << 16);
}

// ---- fused: XCD-partitioned degree histogram + x->bf16 conversion -------
// blocks [0, CNT_BLOCKS): group g = blk&7 only counts dst in its node range,
// so each deg_i line is owned by one XCD's L2 (no cross-XCD line ping-pong).
__global__ __launch_bounds__(256) void k_count_prepx(
    const int* __restrict__ ei, int* __restrict__ deg_i,
    const float* __restrict__ x, uint* __restrict__ xbf) {
  int b = blockIdx.x;
  if (b < CNT_BLOCKS) {
    int g = b & 7;
    int e = (b >> 3) * 256 + threadIdx.x;
    int dst = ei[E + e];
    if ((unsigned)(dst - g * GSZ) < (unsigned)GSZ) atomicAdd(&deg_i[dst], 1);
  } else {
    int t = (b - CNT_BLOCKS) * 256 + threadIdx.x;
    if (t < N * D / 8) {
      const float4* p = (const float4*)(x + (size_t)t * 8);
      float4 a = p[0], c = p[1];
      uint4 o;
      o.x = pack2(a.x, a.y);
      o.y = pack2(a.z, a.w);
      o.z = pack2(c.x, c.y);
      o.w = pack2(c.z, c.w);
      ((uint4*)xbf)[t] = o;
    }
  }
}

// ---- fused: single-block scan (blk 0) + W fragment prep (blk 1) ---------
__global__ __launch_bounds__(1024) void k_scan_prepw(
    const int* __restrict__ deg_i, int* __restrict__ pos,
    float* __restrict__ invdeg, BranchParams P, short* __restrict__ wf) {
  if (blockIdx.x == 1) {  // W -> bf16 MFMA B-fragment order
    int wid = threadIdx.x >> 6;
    int lane = threadIdx.x & 63;
    for (int bfrag = wid; bfrag < 40; bfrag += 16) {
      int br = bfrag >> 3, ct = (bfrag >> 1) & 3, kk = bfrag & 1;
      const float* W = P.W[br];
      int col = ct * 16 + (lane & 15);
      int k0 = kk * 32 + (lane >> 4) * 8;
      s8v v;
#pragma unroll
      for (int j = 0; j < 8; ++j) v[j] = f2bf(W[(k0 + j) * D + col]);
      ((s8v*)wf)[bfrag * 64 + lane] = v;
    }
    return;
  }
  __shared__ int wsum[16];
  __shared__ int carry_s;
  if (threadIdx.x == 0) carry_s = 0;
  __syncthreads();
  const int lane = threadIdx.x & 63;
  const int wid = threadIdx.x >> 6;
  for (int base = 0; base < N; base += 4096) {
    int i0 = base + threadIdx.x * 4;
    int v0 = 0, v1 = 0, v2 = 0, v3 = 0;
    if (i0 + 3 < N) {
      int4 v = *(const int4*)&deg_i[i0];
      v0 = v.x; v1 = v.y; v2 = v.z; v3 = v.w;
    } else {
      if (i0 + 0 < N) v0 = deg_i[i0 + 0];
      if (i0 + 1 < N) v1 = deg_i[i0 + 1];
      if (i0 + 2 < N) v2 = deg_i[i0 + 2];
      if (i0 + 3 < N) v3 = deg_i[i0 + 3];
    }
    int tsum = v0 + v1 + v2 + v3;
    int s = tsum;
#pragma unroll
    for (int o = 1; o < 64; o <<= 1) {
      int t = __shfl_up(s, o);
      if (lane >= o) s += t;
    }
    if (lane == 63) wsum[wid] = s;
    __syncthreads();
    int pre = carry_s;
#pragma unroll
    for (int w = 0; w < 16; ++w) pre += (w < wid) ? wsum[w] : 0;
    int excl = pre + s - tsum;
    if (i0 + 0 < N) { pos[i0 + 0] = excl;                invdeg[i0 + 0] = 1.0f / fmaxf((float)v0, 1.0f); }
    if (i0 + 1 < N) { pos[i0 + 1] = excl + v0;           invdeg[i0 + 1] = 1.0f / fmaxf((float)v1, 1.0f); }
    if (i0 + 2 < N) { pos[i0 + 2] = excl + v0 + v1;      invdeg[i0 + 2] = 1.0f / fmaxf((float)v2, 1.0f); }
    if (i0 + 3 < N) { pos[i0 + 3] = excl + v0 + v1 + v2; invdeg[i0 + 3] = 1.0f / fmaxf((float)v3, 1.0f); }
    __syncthreads();
    if (threadIdx.x == 1023) carry_s = pre + s;
    __syncthreads();
  }
}

// ---- XCD-partitioned CSR fill: group g only scatters dst in its range ---
__global__ __launch_bounds__(256) void k_fill(const int* __restrict__ ei,
                                              int* __restrict__ pos,
                                              ushort* __restrict__ srcs) {
  int g = blockIdx.x & 7;
  int e = (blockIdx.x >> 3) * 256 + threadIdx.x;
  int dst = ei[E + e];
  if ((unsigned)(dst - g * GSZ) < (unsigned)GSZ) {
    int p = atomicAdd(&pos[dst], 1);
    srcs[p] = (ushort)ei[e];
  }
}

// ---- mean aggregation (CSR gather, bf16 rows, 2 edges per instr) --------
__global__ __launch_bounds__(256) void k_agg(
    const int* __restrict__ pos, const ushort* __restrict__ srcs,
    const uint* __restrict__ inbf, const float* __restrict__ invdeg,
    uint* __restrict__ outbf) {
  int node = blockIdx.x * 4 + (threadIdx.x >> 6);
  int lane = threadIdx.x & 63;
  int half = lane >> 5;  // edge parity handled by this half-wave
  int fp = lane & 31;    // feature-pair index
  int start = (node == 0) ? 0 : pos[node - 1];
  int end = pos[node];
  int m = end - start;
  int np = m >> 1;
  float sx = 0.f, sy = 0.f;
  int e = start + half;
  int i = 0;
  for (; i + 2 <= np; i += 2, e += 4) {  // 4 edges in flight
    int s0 = srcs[e], s1 = srcs[e + 2];
    uint v0 = inbf[s0 * 32 + fp];
    uint v1 = inbf[s1 * 32 + fp];
    sx += bflo(v0); sy += bfhi(v0);
    sx += bflo(v1); sy += bfhi(v1);
  }
  if (i < np) {
    int s0 = srcs[e];
    uint v0 = inbf[s0 * 32 + fp];
    sx += bflo(v0); sy += bfhi(v0);
  }
  if ((m & 1) && half == 0) {
    int s0 = srcs[end - 1];
    uint v0 = inbf[s0 * 32 + fp];
    sx += bflo(v0); sy += bfhi(v0);
  }
  sx += __shfl_xor(sx, 32);
  sy += __shfl_xor(sy, 32);
  if (half == 0) {
    float inv = invdeg[node];
    outbf[node * 32 + fp] = pack2(sx * inv, sy * inv);
  }
}

// ---- fused 5-branch MFMA GEMM + ReLU + sigmoid gate + gated sum ---------
__global__ __launch_bounds__(256) void k_branch(
    const ushort* __restrict__ xbf, const ushort* __restrict__ axbf,
    const ushort* __restrict__ aaxbf, BranchParams P,
    const short* __restrict__ wf, float* __restrict__ out) {
  const int lane = threadIdx.x & 63;
  const int wid = threadIdx.x >> 6;
  const int base = blockIdx.x * 64 + wid * 16;
  if (base >= N) return;
  const int l16 = lane & 15;
  const int kg = lane >> 4;

  const s8v* xr = (const s8v*)(xbf + (size_t)(base + l16) * D);
  const s8v* ar = (const s8v*)(axbf + (size_t)(base + l16) * D);
  const s8v* cr = (const s8v*)(aaxbf + (size_t)(base + l16) * D);
  s8v xv[2], av[2], bv[2];
  xv[0] = xr[kg]; xv[1] = xr[4 + kg];
  av[0] = ar[kg]; av[1] = ar[4 + kg];
  bv[0] = cr[kg]; bv[1] = cr[4 + kg];

  s8v hpv[2], hp2v[2];
#pragma unroll
  for (int kk = 0; kk < 2; ++kk) {
#pragma unroll
    for (int j = 0; j < 8; ++j) {
      float fx = bfs(xv[kk][j]), fa = bfs(av[kk][j]), fb = bfs(bv[kk][j]);
      hpv[kk][j] = f2bf(fx - fa);
      hp2v[kk][j] = f2bf(fx - 2.0f * fa + fb);
    }
  }

  f32x4 oacc[4] = {{0.f, 0.f, 0.f, 0.f}, {0.f, 0.f, 0.f, 0.f},
                   {0.f, 0.f, 0.f, 0.f}, {0.f, 0.f, 0.f, 0.f}};
  const s8v* wf8 = (const s8v*)wf;

#pragma unroll
  for (int brn = 0; brn < 5; ++brn) {
    s8v a0, a1;
    switch (brn) {
      case 0: a0 = hpv[0]; a1 = hpv[1]; break;
      case 1: a0 = av[0]; a1 = av[1]; break;
      case 2: a0 = xv[0]; a1 = xv[1]; break;
      case 3: a0 = hp2v[0]; a1 = hp2v[1]; break;
      default: a0 = bv[0]; a1 = bv[1]; break;
    }
    f32x4 acc[4];
#pragma unroll
    for (int ct = 0; ct < 4; ++ct) {
      f32x4 a = {0.f, 0.f, 0.f, 0.f};
      a = __builtin_amdgcn_mfma_f32_16x16x32_bf16(
          a0, wf8[((brn * 4 + ct) * 2 + 0) * 64 + lane], a, 0, 0, 0);
      a = __builtin_amdgcn_mfma_f32_16x16x32_bf16(
          a1, wf8[((brn * 4 + ct) * 2 + 1) * 64 + lane], a, 0, 0, 0);
      acc[ct] = a;
    }
    float bcol[4], wacol[4];
#pragma unroll
    for (int ct = 0; ct < 4; ++ct) {
      bcol[ct] = P.b[brn][ct * 16 + l16];
      wacol[ct] = P.wa[brn][ct * 16 + l16];
    }
    const float bav = P.ba[brn][0];
#pragma unroll
    for (int i = 0; i < 4; ++i) {
      float h[4], g = 0.f;
#pragma unroll
      for (int ct = 0; ct < 4; ++ct) {
        h[ct] = fmaxf(acc[ct][i] + bcol[ct], 0.f);
        g = fmaf(h[ct], wacol[ct], g);
      }
#pragma unroll
      for (int o = 1; o < 16; o <<= 1) g += __shfl_xor(g, o);
      float alpha = 1.0f / (1.0f + __expf(-(g + bav)));
#pragma unroll
      for (int ct = 0; ct < 4; ++ct) oacc[ct][i] = fmaf(alpha, h[ct], oacc[ct][i]);
    }
  }
#pragma unroll
  for (int ct = 0; ct < 4; ++ct)
#pragma unroll
    for (int i = 0; i < 4; ++i)
      out[(size_t)(base + kg * 4 + i) * D + ct * 16 + l16] = oacc[ct][i];
}

extern "C" void kernel_launch(void* const* d_in, const int* in_sizes, int n_in,
                              void* d_out, int out_size, void* d_ws, size_t ws_size,
                              hipStream_t stream) {
  const float* x = (const float*)d_in[0];
  const int* ei = (const int*)d_in[1];
  BranchParams P;
  for (int i = 0; i < 5; ++i) {
    P.W[i] = (const float*)d_in[2 + 4 * i];
    P.b[i] = (const float*)d_in[3 + 4 * i];
    P.wa[i] = (const float*)d_in[4 + 4 * i];
    P.ba[i] = (const float*)d_in[5 + 4 * i];
  }

  char* w = (char*)d_ws;
  uint* xbf = (uint*)w;                          w += (size_t)N * D * 2;
  uint* axbf = (uint*)w;                         w += (size_t)N * D * 2;
  uint* aaxbf = (uint*)w;                        w += (size_t)N * D * 2;
  float* invdeg = (float*)w;                     w += (size_t)N * 4;
  int* deg_i = (int*)w;                          w += (size_t)N * 4;
  int* pos = (int*)w;                            w += (size_t)N * 4;
  ushort* srcs = (ushort*)w;                     w += (size_t)E * 2;
  short* wf = (short*)w;

  hipMemsetAsync(deg_i, 0, (size_t)N * sizeof(int), stream);

  hipLaunchKernelGGL(k_count_prepx, dim3(CNT_BLOCKS + PREPX_BLOCKS), dim3(256),
                     0, stream, ei, deg_i, x, xbf);
  hipLaunchKernelGGL(k_scan_prepw, dim3(2), dim3(1024), 0, stream,
                     deg_i, pos, invdeg, P, wf);
  hipLaunchKernelGGL(k_fill, dim3(EBLK * 8), dim3(256), 0, stream, ei, pos, srcs);
  hipLaunchKernelGGL(k_agg, dim3(N / 4), dim3(256), 0, stream, pos, srcs, xbf, invdeg, axbf);
  hipLaunchKernelGGL(k_agg, dim3(N / 4), dim3(256), 0, stream, pos, srcs, axbf, invdeg, aaxbf);
  hipLaunchKernelGGL(k_branch, dim3((N + 63) / 64), dim3(256), 0, stream,
                     (const ushort*)xbf, (const ushort*)axbf, (const ushort*)aaxbf,
                     P, wf, (float*)d_out);
}

// Round 6
// 176.316 us; speedup vs baseline: 2.7516x; 1.0116x over previous
//
#include <hip/hip_runtime.h>
#include <hip/hip_bf16.h>

constexpr int N = 50000;
constexpr int E = 800000;
constexpr int D = 64;
constexpr int GSZ = N / 8;                    // 6250 nodes per XCD group
constexpr int EBLK = E / 256;                 // 3125 edge chunks
constexpr int CNT_BLOCKS = EBLK * 8;          // count replicas
constexpr int PREPX_BLOCKS = (N * D / 8 + 255) / 256;  // 1563

typedef __attribute__((ext_vector_type(8))) short s8v;    // 8 bf16 (4 VGPRs)
typedef __attribute__((ext_vector_type(4))) float f32x4;  // mfma accumulator

struct BranchParams {
  const float* W[5];
  const float* b[5];
  const float* wa[5];
  const float* ba[5];
};

__device__ inline short f2bf(float f) {  // RNE float->bf16 bits
  unsigned u = __float_as_uint(f);
  u += 0x7fff + ((u >> 16) & 1);
  return (short)(u >> 16);
}
__device__ inline float bflo(unsigned v) { return __uint_as_float(v << 16); }
__device__ inline float bfhi(unsigned v) { return __uint_as_float(v & 0xffff0000u); }
__device__ inline float bfs(short s) {
  return __uint_as_float(((unsigned)(unsigned short)s) << 16);
}
__device__ inline unsigned pack2(float lo, float hi) {
  return ((unsigned)(unsigned short)f2bf(lo)) |
         (((unsigned)(unsigned short)f2bf(hi)) << 16);
}

// ---- zero the degree histogram (replaces runtime fillBufferAligned) -----
__global__ __launch_bounds__(256) void k_zero(int4* __restrict__ deg4) {
  int t = blockIdx.x * 256 + threadIdx.x;
  if (t < N / 4) deg4[t] = int4{0, 0, 0, 0};  // N = 50000 = 12500 * 4
}

// ---- fused: XCD-partitioned degree histogram + x->bf16 conversion -------
__global__ __launch_bounds__(256) void k_count_prepx(
    const int* __restrict__ ei, int* __restrict__ deg_i,
    const float* __restrict__ x, uint* __restrict__ xbf) {
  int b = blockIdx.x;
  if (b < CNT_BLOCKS) {
    int g = b & 7;
    int e = (b >> 3) * 256 + threadIdx.x;
    int dst = ei[E + e];
    if ((unsigned)(dst - g * GSZ) < (unsigned)GSZ) atomicAdd(&deg_i[dst], 1);
  } else {
    int t = (b - CNT_BLOCKS) * 256 + threadIdx.x;
    if (t < N * D / 8) {
      const float4* p = (const float4*)(x + (size_t)t * 8);
      float4 a = p[0], c = p[1];
      uint4 o;
      o.x = pack2(a.x, a.y);
      o.y = pack2(a.z, a.w);
      o.z = pack2(c.x, c.y);
      o.w = pack2(c.z, c.w);
      ((uint4*)xbf)[t] = o;
    }
  }
}

// ---- fused: single-block scan (blk 0) + W fragment prep (blk 1) ---------
__global__ __launch_bounds__(1024) void k_scan_prepw(
    const int* __restrict__ deg_i, int* __restrict__ pos,
    float* __restrict__ invdeg, BranchParams P, short* __restrict__ wf) {
  if (blockIdx.x == 1) {  // W -> bf16 MFMA B-fragment order
    int wid = threadIdx.x >> 6;
    int lane = threadIdx.x & 63;
    for (int bfrag = wid; bfrag < 40; bfrag += 16) {
      int br = bfrag >> 3, ct = (bfrag >> 1) & 3, kk = bfrag & 1;
      const float* W = P.W[br];
      int col = ct * 16 + (lane & 15);
      int k0 = kk * 32 + (lane >> 4) * 8;
      s8v v;
#pragma unroll
      for (int j = 0; j < 8; ++j) v[j] = f2bf(W[(k0 + j) * D + col]);
      ((s8v*)wf)[bfrag * 64 + lane] = v;
    }
    return;
  }
  __shared__ int wsum[16];
  __shared__ int carry_s;
  if (threadIdx.x == 0) carry_s = 0;
  __syncthreads();
  const int lane = threadIdx.x & 63;
  const int wid = threadIdx.x >> 6;
  for (int base = 0; base < N; base += 4096) {
    int i0 = base + threadIdx.x * 4;
    int v0 = 0, v1 = 0, v2 = 0, v3 = 0;
    if (i0 + 3 < N) {
      int4 v = *(const int4*)&deg_i[i0];
      v0 = v.x; v1 = v.y; v2 = v.z; v3 = v.w;
    } else {
      if (i0 + 0 < N) v0 = deg_i[i0 + 0];
      if (i0 + 1 < N) v1 = deg_i[i0 + 1];
      if (i0 + 2 < N) v2 = deg_i[i0 + 2];
      if (i0 + 3 < N) v3 = deg_i[i0 + 3];
    }
    int tsum = v0 + v1 + v2 + v3;
    int s = tsum;
#pragma unroll
    for (int o = 1; o < 64; o <<= 1) {
      int t = __shfl_up(s, o);
      if (lane >= o) s += t;
    }
    if (lane == 63) wsum[wid] = s;
    __syncthreads();
    int pre = carry_s;
#pragma unroll
    for (int w = 0; w < 16; ++w) pre += (w < wid) ? wsum[w] : 0;
    int excl = pre + s - tsum;
    if (i0 + 0 < N) { pos[i0 + 0] = excl;                invdeg[i0 + 0] = 1.0f / fmaxf((float)v0, 1.0f); }
    if (i0 + 1 < N) { pos[i0 + 1] = excl + v0;           invdeg[i0 + 1] = 1.0f / fmaxf((float)v1, 1.0f); }
    if (i0 + 2 < N) { pos[i0 + 2] = excl + v0 + v1;      invdeg[i0 + 2] = 1.0f / fmaxf((float)v2, 1.0f); }
    if (i0 + 3 < N) { pos[i0 + 3] = excl + v0 + v1 + v2; invdeg[i0 + 3] = 1.0f / fmaxf((float)v3, 1.0f); }
    __syncthreads();
    if (threadIdx.x == 1023) carry_s = pre + s;
    __syncthreads();
  }
}

// ---- XCD-partitioned CSR fill ------------------------------------------
__global__ __launch_bounds__(256) void k_fill(const int* __restrict__ ei,
                                              int* __restrict__ pos,
                                              ushort* __restrict__ srcs) {
  int g = blockIdx.x & 7;
  int e = (blockIdx.x >> 3) * 256 + threadIdx.x;
  int dst = ei[E + e];
  if ((unsigned)(dst - g * GSZ) < (unsigned)GSZ) {
    int p = atomicAdd(&pos[dst], 1);
    srcs[p] = (ushort)ei[e];
  }
}

// ---- mean aggregation (CSR gather, bf16 rows, 2 edges per instr) --------
__global__ __launch_bounds__(256) void k_agg(
    const int* __restrict__ pos, const ushort* __restrict__ srcs,
    const uint* __restrict__ inbf, const float* __restrict__ invdeg,
    uint* __restrict__ outbf) {
  int node = blockIdx.x * 4 + (threadIdx.x >> 6);
  int lane = threadIdx.x & 63;
  int half = lane >> 5;  // edge parity handled by this half-wave
  int fp = lane & 31;    // feature-pair index
  int start = (node == 0) ? 0 : pos[node - 1];
  int end = pos[node];
  int m = end - start;
  int np = m >> 1;
  float sx = 0.f, sy = 0.f;
  int e = start + half;
  int i = 0;
  for (; i + 2 <= np; i += 2, e += 4) {  // 4 edges in flight
    int s0 = srcs[e], s1 = srcs[e + 2];
    uint v0 = inbf[s0 * 32 + fp];
    uint v1 = inbf[s1 * 32 + fp];
    sx += bflo(v0); sy += bfhi(v0);
    sx += bflo(v1); sy += bfhi(v1);
  }
  if (i < np) {
    int s0 = srcs[e];
    uint v0 = inbf[s0 * 32 + fp];
    sx += bflo(v0); sy += bfhi(v0);
  }
  if ((m & 1) && half == 0) {
    int s0 = srcs[end - 1];
    uint v0 = inbf[s0 * 32 + fp];
    sx += bflo(v0); sy += bfhi(v0);
  }
  sx += __shfl_xor(sx, 32);
  sy += __shfl_xor(sy, 32);
  if (half == 0) {
    float inv = invdeg[node];
    outbf[node * 32 + fp] = pack2(sx * inv, sy * inv);
  }
}

// ---- fused 5-branch MFMA GEMM + ReLU + sigmoid gate + gated sum ---------
__global__ __launch_bounds__(256) void k_branch(
    const ushort* __restrict__ xbf, const ushort* __restrict__ axbf,
    const ushort* __restrict__ aaxbf, BranchParams P,
    const short* __restrict__ wf, float* __restrict__ out) {
  const int lane = threadIdx.x & 63;
  const int wid = threadIdx.x >> 6;
  const int base = blockIdx.x * 64 + wid * 16;
  if (base >= N) return;
  const int l16 = lane & 15;
  const int kg = lane >> 4;

  const s8v* xr = (const s8v*)(xbf + (size_t)(base + l16) * D);
  const s8v* ar = (const s8v*)(axbf + (size_t)(base + l16) * D);
  const s8v* cr = (const s8v*)(aaxbf + (size_t)(base + l16) * D);
  s8v xv[2], av[2], bv[2];
  xv[0] = xr[kg]; xv[1] = xr[4 + kg];
  av[0] = ar[kg]; av[1] = ar[4 + kg];
  bv[0] = cr[kg]; bv[1] = cr[4 + kg];

  s8v hpv[2], hp2v[2];
#pragma unroll
  for (int kk = 0; kk < 2; ++kk) {
#pragma unroll
    for (int j = 0; j < 8; ++j) {
      float fx = bfs(xv[kk][j]), fa = bfs(av[kk][j]), fb = bfs(bv[kk][j]);
      hpv[kk][j] = f2bf(fx - fa);
      hp2v[kk][j] = f2bf(fx - 2.0f * fa + fb);
    }
  }

  f32x4 oacc[4] = {{0.f, 0.f, 0.f, 0.f}, {0.f, 0.f, 0.f, 0.f},
                   {0.f, 0.f, 0.f, 0.f}, {0.f, 0.f, 0.f, 0.f}};
  const s8v* wf8 = (const s8v*)wf;

#pragma unroll
  for (int brn = 0; brn < 5; ++brn) {
    s8v a0, a1;
    switch (brn) {
      case 0: a0 = hpv[0]; a1 = hpv[1]; break;
      case 1: a0 = av[0]; a1 = av[1]; break;
      case 2: a0 = xv[0]; a1 = xv[1]; break;
      case 3: a0 = hp2v[0]; a1 = hp2v[1]; break;
      default: a0 = bv[0]; a1 = bv[1]; break;
    }
    f32x4 acc[4];
#pragma unroll
    for (int ct = 0; ct < 4; ++ct) {
      f32x4 a = {0.f, 0.f, 0.f, 0.f};
      a = __builtin_amdgcn_mfma_f32_16x16x32_bf16(
          a0, wf8[((brn * 4 + ct) * 2 + 0) * 64 + lane], a, 0, 0, 0);
      a = __builtin_amdgcn_mfma_f32_16x16x32_bf16(
          a1, wf8[((brn * 4 + ct) * 2 + 1) * 64 + lane], a, 0, 0, 0);
      acc[ct] = a;
    }
    float bcol[4], wacol[4];
#pragma unroll
    for (int ct = 0; ct < 4; ++ct) {
      bcol[ct] = P.b[brn][ct * 16 + l16];
      wacol[ct] = P.wa[brn][ct * 16 + l16];
    }
    const float bav = P.ba[brn][0];
#pragma unroll
    for (int i = 0; i < 4; ++i) {
      float h[4], g = 0.f;
#pragma unroll
      for (int ct = 0; ct < 4; ++ct) {
        h[ct] = fmaxf(acc[ct][i] + bcol[ct], 0.f);
        g = fmaf(h[ct], wacol[ct], g);
      }
#pragma unroll
      for (int o = 1; o < 16; o <<= 1) g += __shfl_xor(g, o);
      float alpha = 1.0f / (1.0f + __expf(-(g + bav)));
#pragma unroll
      for (int ct = 0; ct < 4; ++ct) oacc[ct][i] = fmaf(alpha, h[ct], oacc[ct][i]);
    }
  }
#pragma unroll
  for (int ct = 0; ct < 4; ++ct)
#pragma unroll
    for (int i = 0; i < 4; ++i)
      out[(size_t)(base + kg * 4 + i) * D + ct * 16 + l16] = oacc[ct][i];
}

extern "C" void kernel_launch(void* const* d_in, const int* in_sizes, int n_in,
                              void* d_out, int out_size, void* d_ws, size_t ws_size,
                              hipStream_t stream) {
  const float* x = (const float*)d_in[0];
  const int* ei = (const int*)d_in[1];
  BranchParams P;
  for (int i = 0; i < 5; ++i) {
    P.W[i] = (const float*)d_in[2 + 4 * i];
    P.b[i] = (const float*)d_in[3 + 4 * i];
    P.wa[i] = (const float*)d_in[4 + 4 * i];
    P.ba[i] = (const float*)d_in[5 + 4 * i];
  }

  char* w = (char*)d_ws;
  uint* xbf = (uint*)w;                          w += (size_t)N * D * 2;
  uint* axbf = (uint*)w;                         w += (size_t)N * D * 2;
  uint* aaxbf = (uint*)w;                        w += (size_t)N * D * 2;
  float* invdeg = (float*)w;                     w += (size_t)N * 4;
  int* deg_i = (int*)w;                          w += (size_t)N * 4;
  int* pos = (int*)w;                            w += (size_t)N * 4;
  ushort* srcs = (ushort*)w;                     w += (size_t)E * 2;
  short* wf = (short*)w;

  hipLaunchKernelGGL(k_zero, dim3((N / 4 + 255) / 256), dim3(256), 0, stream,
                     (int4*)deg_i);
  hipLaunchKernelGGL(k_count_prepx, dim3(CNT_BLOCKS + PREPX_BLOCKS), dim3(256),
                     0, stream, ei, deg_i, x, xbf);
  hipLaunchKernelGGL(k_scan_prepw, dim3(2), dim3(1024), 0, stream,
                     deg_i, pos, invdeg, P, wf);
  hipLaunchKernelGGL(k_fill, dim3(EBLK * 8), dim3(256), 0, stream, ei, pos, srcs);
  hipLaunchKernelGGL(k_agg, dim3(N / 4), dim3(256), 0, stream, pos, srcs, xbf, invdeg, axbf);
  hipLaunchKernelGGL(k_agg, dim3(N / 4), dim3(256), 0, stream, pos, srcs, axbf, invdeg, aaxbf);
  hipLaunchKernelGGL(k_branch, dim3((N + 63) / 64), dim3(256), 0, stream,
                     (const ushort*)xbf, (const ushort*)axbf, (const ushort*)aaxbf,
                     P, wf, (float*)d_out);
}

// Round 7
// 175.978 us; speedup vs baseline: 2.7569x; 1.0019x over previous
//
#include <hip/hip_runtime.h>
#include <hip/hip_bf16.h>

constexpr int N = 50000;
constexpr int E = 800000;
constexpr int D = 64;
constexpr int GSZ = N / 8;            // 6250 nodes per XCD group
constexpr int CAP = 131072;           // tokens per bucket (expect ~100k)
constexpr int CBLK = CAP / 256;       // 512 blocks per bucket
constexpr int PREPX_BLOCKS = (N * D / 8 + 255) / 256;  // 1563

typedef __attribute__((ext_vector_type(8))) short s8v;    // 8 bf16 (4 VGPRs)
typedef __attribute__((ext_vector_type(4))) float f32x4;  // mfma accumulator

struct BranchParams {
  const float* W[5];
  const float* b[5];
  const float* wa[5];
  const float* ba[5];
};

__device__ inline short f2bf(float f) {  // RNE float->bf16 bits
  unsigned u = __float_as_uint(f);
  u += 0x7fff + ((u >> 16) & 1);
  return (short)(u >> 16);
}
__device__ inline float bflo(unsigned v) { return __uint_as_float(v << 16); }
__device__ inline float bfhi(unsigned v) { return __uint_as_float(v & 0xffff0000u); }
__device__ inline float bfs(short s) {
  return __uint_as_float(((unsigned)(unsigned short)s) << 16);
}
__device__ inline unsigned pack2(float lo, float hi) {
  return ((unsigned)(unsigned short)f2bf(lo)) |
         (((unsigned)(unsigned short)f2bf(hi)) << 16);
}

// ---- zero degree histogram + bucket cursors -----------------------------
__global__ __launch_bounds__(256) void k_zero(int4* __restrict__ deg4,
                                              int4* __restrict__ bc4) {
  int t = blockIdx.x * 256 + threadIdx.x;
  if (t < N / 4) deg4[t] = int4{0, 0, 0, 0};        // 12500
  else if (t < N / 4 + 64) bc4[t - N / 4] = int4{0, 0, 0, 0};  // 8*32 ints
}

// ---- single-pass edge bucketing by dst/6250 (XCD owner group) -----------
// token = (src << 13) | dstloc ; src < 2^16, dstloc < 6250 < 2^13
__global__ __launch_bounds__(1024) void k_bucket(const int* __restrict__ ei,
                                                 uint* __restrict__ bktBuf,
                                                 int* __restrict__ bktCnt) {
  __shared__ int lcnt[8], lbase[8];
  int e = blockIdx.x * 1024 + threadIdx.x;
  if (threadIdx.x < 8) lcnt[threadIdx.x] = 0;
  __syncthreads();
  int src = 0, g = 8, dstloc = 0, slot = 0;
  if (e < E) {
    src = ei[e];
    int dst = ei[E + e];
    g = dst / GSZ;
    dstloc = dst - g * GSZ;
    slot = atomicAdd(&lcnt[g], 1);
  }
  __syncthreads();
  if (threadIdx.x < 8)
    lbase[threadIdx.x] = atomicAdd(&bktCnt[threadIdx.x * 32], lcnt[threadIdx.x]);
  __syncthreads();
  if (e < E)
    bktBuf[(size_t)g * CAP + lbase[g] + slot] = ((uint)src << 13) | (uint)dstloc;
}

// ---- fused: XCD-local degree count from tokens + x->bf16 conversion -----
__global__ __launch_bounds__(256) void k_count_prepx(
    const uint* __restrict__ bktBuf, const int* __restrict__ bktCnt,
    int* __restrict__ deg_i, const float* __restrict__ x,
    uint* __restrict__ xbf) {
  int b = blockIdx.x;
  if (b < 8 * CBLK) {
    int g = b & 7;  // block -> XCD g owns deg slice [g*GSZ, (g+1)*GSZ)
    int idx = (b >> 3) * 256 + threadIdx.x;
    if (idx < bktCnt[g * 32]) {
      uint tok = bktBuf[(size_t)g * CAP + idx];
      atomicAdd(&deg_i[g * GSZ + (int)(tok & 8191u)], 1);
    }
  } else {
    int t = (b - 8 * CBLK) * 256 + threadIdx.x;
    if (t < N * D / 8) {
      const float4* p = (const float4*)(x + (size_t)t * 8);
      float4 a = p[0], c = p[1];
      uint4 o;
      o.x = pack2(a.x, a.y);
      o.y = pack2(a.z, a.w);
      o.z = pack2(c.x, c.y);
      o.w = pack2(c.z, c.w);
      ((uint4*)xbf)[t] = o;
    }
  }
}

// ---- fused: single-block scan (blk 0) + W fragment prep (blk 1) ---------
__global__ __launch_bounds__(1024) void k_scan_prepw(
    const int* __restrict__ deg_i, int* __restrict__ pos,
    float* __restrict__ invdeg, BranchParams P, short* __restrict__ wf) {
  if (blockIdx.x == 1) {  // W -> bf16 MFMA B-fragment order
    int wid = threadIdx.x >> 6;
    int lane = threadIdx.x & 63;
    for (int bfrag = wid; bfrag < 40; bfrag += 16) {
      int br = bfrag >> 3, ct = (bfrag >> 1) & 3, kk = bfrag & 1;
      const float* W = P.W[br];
      int col = ct * 16 + (lane & 15);
      int k0 = kk * 32 + (lane >> 4) * 8;
      s8v v;
#pragma unroll
      for (int j = 0; j < 8; ++j) v[j] = f2bf(W[(k0 + j) * D + col]);
      ((s8v*)wf)[bfrag * 64 + lane] = v;
    }
    return;
  }
  __shared__ int wsum[16];
  __shared__ int carry_s;
  if (threadIdx.x == 0) carry_s = 0;
  __syncthreads();
  const int lane = threadIdx.x & 63;
  const int wid = threadIdx.x >> 6;
  for (int base = 0; base < N; base += 4096) {
    int i0 = base + threadIdx.x * 4;
    int v0 = 0, v1 = 0, v2 = 0, v3 = 0;
    if (i0 + 3 < N) {
      int4 v = *(const int4*)&deg_i[i0];
      v0 = v.x; v1 = v.y; v2 = v.z; v3 = v.w;
    } else {
      if (i0 + 0 < N) v0 = deg_i[i0 + 0];
      if (i0 + 1 < N) v1 = deg_i[i0 + 1];
      if (i0 + 2 < N) v2 = deg_i[i0 + 2];
      if (i0 + 3 < N) v3 = deg_i[i0 + 3];
    }
    int tsum = v0 + v1 + v2 + v3;
    int s = tsum;
#pragma unroll
    for (int o = 1; o < 64; o <<= 1) {
      int t = __shfl_up(s, o);
      if (lane >= o) s += t;
    }
    if (lane == 63) wsum[wid] = s;
    __syncthreads();
    int pre = carry_s;
#pragma unroll
    for (int w = 0; w < 16; ++w) pre += (w < wid) ? wsum[w] : 0;
    int excl = pre + s - tsum;
    if (i0 + 0 < N) { pos[i0 + 0] = excl;                invdeg[i0 + 0] = 1.0f / fmaxf((float)v0, 1.0f); }
    if (i0 + 1 < N) { pos[i0 + 1] = excl + v0;           invdeg[i0 + 1] = 1.0f / fmaxf((float)v1, 1.0f); }
    if (i0 + 2 < N) { pos[i0 + 2] = excl + v0 + v1;      invdeg[i0 + 2] = 1.0f / fmaxf((float)v2, 1.0f); }
    if (i0 + 3 < N) { pos[i0 + 3] = excl + v0 + v1 + v2; invdeg[i0 + 3] = 1.0f / fmaxf((float)v3, 1.0f); }
    __syncthreads();
    if (threadIdx.x == 1023) carry_s = pre + s;
    __syncthreads();
  }
}

// ---- XCD-local CSR fill from tokens -------------------------------------
__global__ __launch_bounds__(256) void k_fill(const uint* __restrict__ bktBuf,
                                              const int* __restrict__ bktCnt,
                                              int* __restrict__ pos,
                                              ushort* __restrict__ srcs) {
  int g = blockIdx.x & 7;
  int idx = (blockIdx.x >> 3) * 256 + threadIdx.x;
  if (idx < bktCnt[g * 32]) {
    uint tok = bktBuf[(size_t)g * CAP + idx];
    int dst = g * GSZ + (int)(tok & 8191u);
    int p = atomicAdd(&pos[dst], 1);
    srcs[p] = (ushort)(tok >> 13);
  }
}

// ---- mean aggregation (CSR gather, bf16 rows, 8 rows in flight) ---------
__global__ __launch_bounds__(256) void k_agg(
    const int* __restrict__ pos, const ushort* __restrict__ srcs,
    const uint* __restrict__ inbf, const float* __restrict__ invdeg,
    uint* __restrict__ outbf) {
  int node = blockIdx.x * 4 + (threadIdx.x >> 6);
  int lane = threadIdx.x & 63;
  int half = lane >> 5;  // edge parity handled by this half-wave
  int fp = lane & 31;    // feature-pair index
  int start = (node == 0) ? 0 : pos[node - 1];
  int end = pos[node];
  int m = end - start;
  int np = m >> 1;
  float sx0 = 0.f, sy0 = 0.f, sx1 = 0.f, sy1 = 0.f;
  float sx2 = 0.f, sy2 = 0.f, sx3 = 0.f, sy3 = 0.f;
  int e = start + half;
  int i = 0;
  for (; i + 4 <= np; i += 4, e += 8) {  // 8 row-gathers in flight per wave
    int s0 = srcs[e], s1 = srcs[e + 2], s2 = srcs[e + 4], s3 = srcs[e + 6];
    uint v0 = inbf[s0 * 32 + fp];
    uint v1 = inbf[s1 * 32 + fp];
    uint v2 = inbf[s2 * 32 + fp];
    uint v3 = inbf[s3 * 32 + fp];
    sx0 += bflo(v0); sy0 += bfhi(v0);
    sx1 += bflo(v1); sy1 += bfhi(v1);
    sx2 += bflo(v2); sy2 += bfhi(v2);
    sx3 += bflo(v3); sy3 += bfhi(v3);
  }
  for (; i < np; ++i, e += 2) {
    int s0 = srcs[e];
    uint v0 = inbf[s0 * 32 + fp];
    sx0 += bflo(v0); sy0 += bfhi(v0);
  }
  if ((m & 1) && half == 0) {  // odd tail: half 0 only
    int s0 = srcs[end - 1];
    uint v0 = inbf[s0 * 32 + fp];
    sx0 += bflo(v0); sy0 += bfhi(v0);
  }
  float sx = (sx0 + sx1) + (sx2 + sx3);
  float sy = (sy0 + sy1) + (sy2 + sy3);
  sx += __shfl_xor(sx, 32);
  sy += __shfl_xor(sy, 32);
  if (half == 0) {
    float inv = invdeg[node];
    outbf[node * 32 + fp] = pack2(sx * inv, sy * inv);
  }
}

// ---- fused 5-branch MFMA GEMM + ReLU + sigmoid gate + gated sum ---------
__global__ __launch_bounds__(256) void k_branch(
    const ushort* __restrict__ xbf, const ushort* __restrict__ axbf,
    const ushort* __restrict__ aaxbf, BranchParams P,
    const short* __restrict__ wf, float* __restrict__ out) {
  const int lane = threadIdx.x & 63;
  const int wid = threadIdx.x >> 6;
  const int base = blockIdx.x * 64 + wid * 16;
  if (base >= N) return;
  const int l16 = lane & 15;
  const int kg = lane >> 4;

  const s8v* xr = (const s8v*)(xbf + (size_t)(base + l16) * D);
  const s8v* ar = (const s8v*)(axbf + (size_t)(base + l16) * D);
  const s8v* cr = (const s8v*)(aaxbf + (size_t)(base + l16) * D);
  s8v xv[2], av[2], bv[2];
  xv[0] = xr[kg]; xv[1] = xr[4 + kg];
  av[0] = ar[kg]; av[1] = ar[4 + kg];
  bv[0] = cr[kg]; bv[1] = cr[4 + kg];

  s8v hpv[2], hp2v[2];
#pragma unroll
  for (int kk = 0; kk < 2; ++kk) {
#pragma unroll
    for (int j = 0; j < 8; ++j) {
      float fx = bfs(xv[kk][j]), fa = bfs(av[kk][j]), fb = bfs(bv[kk][j]);
      hpv[kk][j] = f2bf(fx - fa);
      hp2v[kk][j] = f2bf(fx - 2.0f * fa + fb);
    }
  }

  f32x4 oacc[4] = {{0.f, 0.f, 0.f, 0.f}, {0.f, 0.f, 0.f, 0.f},
                   {0.f, 0.f, 0.f, 0.f}, {0.f, 0.f, 0.f, 0.f}};
  const s8v* wf8 = (const s8v*)wf;

#pragma unroll
  for (int brn = 0; brn < 5; ++brn) {
    s8v a0, a1;
    switch (brn) {
      case 0: a0 = hpv[0]; a1 = hpv[1]; break;
      case 1: a0 = av[0]; a1 = av[1]; break;
      case 2: a0 = xv[0]; a1 = xv[1]; break;
      case 3: a0 = hp2v[0]; a1 = hp2v[1]; break;
      default: a0 = bv[0]; a1 = bv[1]; break;
    }
    f32x4 acc[4];
#pragma unroll
    for (int ct = 0; ct < 4; ++ct) {
      f32x4 a = {0.f, 0.f, 0.f, 0.f};
      a = __builtin_amdgcn_mfma_f32_16x16x32_bf16(
          a0, wf8[((brn * 4 + ct) * 2 + 0) * 64 + lane], a, 0, 0, 0);
      a = __builtin_amdgcn_mfma_f32_16x16x32_bf16(
          a1, wf8[((brn * 4 + ct) * 2 + 1) * 64 + lane], a, 0, 0, 0);
      acc[ct] = a;
    }
    float bcol[4], wacol[4];
#pragma unroll
    for (int ct = 0; ct < 4; ++ct) {
      bcol[ct] = P.b[brn][ct * 16 + l16];
      wacol[ct] = P.wa[brn][ct * 16 + l16];
    }
    const float bav = P.ba[brn][0];
#pragma unroll
    for (int i = 0; i < 4; ++i) {
      float h[4], g = 0.f;
#pragma unroll
      for (int ct = 0; ct < 4; ++ct) {
        h[ct] = fmaxf(acc[ct][i] + bcol[ct], 0.f);
        g = fmaf(h[ct], wacol[ct], g);
      }
#pragma unroll
      for (int o = 1; o < 16; o <<= 1) g += __shfl_xor(g, o);
      float alpha = 1.0f / (1.0f + __expf(-(g + bav)));
#pragma unroll
      for (int ct = 0; ct < 4; ++ct) oacc[ct][i] = fmaf(alpha, h[ct], oacc[ct][i]);
    }
  }
#pragma unroll
  for (int ct = 0; ct < 4; ++ct)
#pragma unroll
    for (int i = 0; i < 4; ++i)
      out[(size_t)(base + kg * 4 + i) * D + ct * 16 + l16] = oacc[ct][i];
}

extern "C" void kernel_launch(void* const* d_in, const int* in_sizes, int n_in,
                              void* d_out, int out_size, void* d_ws, size_t ws_size,
                              hipStream_t stream) {
  const float* x = (const float*)d_in[0];
  const int* ei = (const int*)d_in[1];
  BranchParams P;
  for (int i = 0; i < 5; ++i) {
    P.W[i] = (const float*)d_in[2 + 4 * i];
    P.b[i] = (const float*)d_in[3 + 4 * i];
    P.wa[i] = (const float*)d_in[4 + 4 * i];
    P.ba[i] = (const float*)d_in[5 + 4 * i];
  }

  char* w = (char*)d_ws;
  uint* xbf = (uint*)w;                          w += (size_t)N * D * 2;
  uint* axbf = (uint*)w;                         w += (size_t)N * D * 2;
  uint* aaxbf = (uint*)w;                        w += (size_t)N * D * 2;
  float* invdeg = (float*)w;                     w += (size_t)N * 4;
  int* deg_i = (int*)w;                          w += (size_t)N * 4;
  int* pos = (int*)w;                            w += (size_t)N * 4;
  ushort* srcs = (ushort*)w;                     w += (size_t)E * 2;
  short* wf = (short*)w;                         w += 40 * 512 * 2;
  int* bktCnt = (int*)w;                         w += 8 * 32 * 4;  // padded cursors
  uint* bktBuf = (uint*)w;                       // 8 * CAP * 4 = 4 MB

  hipLaunchKernelGGL(k_zero, dim3((N / 4 + 64 + 255) / 256), dim3(256), 0, stream,
                     (int4*)deg_i, (int4*)bktCnt);
  hipLaunchKernelGGL(k_bucket, dim3((E + 1023) / 1024), dim3(1024), 0, stream,
                     ei, bktBuf, bktCnt);
  hipLaunchKernelGGL(k_count_prepx, dim3(8 * CBLK + PREPX_BLOCKS), dim3(256),
                     0, stream, bktBuf, bktCnt, deg_i, x, xbf);
  hipLaunchKernelGGL(k_scan_prepw, dim3(2), dim3(1024), 0, stream,
                     deg_i, pos, invdeg, P, wf);
  hipLaunchKernelGGL(k_fill, dim3(8 * CBLK), dim3(256), 0, stream,
                     bktBuf, bktCnt, pos, srcs);
  hipLaunchKernelGGL(k_agg, dim3(N / 4), dim3(256), 0, stream, pos, srcs, xbf, invdeg, axbf);
  hipLaunchKernelGGL(k_agg, dim3(N / 4), dim3(256), 0, stream, pos, srcs, axbf, invdeg, aaxbf);
  hipLaunchKernelGGL(k_branch, dim3((N + 63) / 64), dim3(256), 0, stream,
                     (const ushort*)xbf, (const ushort*)axbf, (const ushort*)aaxbf,
                     P, wf, (float*)d_out);
}